// Round 6
// baseline (166493.335 us; speedup 1.0000x reference)
//
#include <hip/hip_runtime.h>
#include <stdint.h>

// R13: R12 base (coalesced h-publish, 17.53ms) + 2-deep pipelined poll with
// the rule-#18 fix. R11's version of this regressed 8x because hipcc hoisted
// the register-only tag-check VALU above the split-off inline-asm s_waitcnt
// ("memory" clobber doesn't order non-memory VALU). Fix per learn_hip m214
// r263/r282: __builtin_amdgcn_sched_barrier(0) immediately after EVERY
// inline-asm waitcnt -- a bidirectional compile-time scheduling fence.
// Theory: consumer detect leg is sampling-period-bound (serial load->wait->
// check = full MALL round trip per sample; staging barrier waits on the max
// over 256 independently-phased pollers). Two loads in flight + vmcnt(1)
// retirement halves the sampling period and the max-tail with it.

#define S_LEN 8192
#define HID   1024
#define DIN0  256
#define NL    4
#define NCU_L 64
#define NTHR  512
#define NWAVE 8
#define SP    128          // weight dwords per lane per wave
#define RING  128
#define RMASK (RING - 1)

typedef _Float16 half2v __attribute__((ext_vector_type(2)));
typedef uint32_t v4u   __attribute__((ext_vector_type(4)));

#if defined(__has_builtin)
#if __has_builtin(__builtin_amdgcn_fdot2)
#define HAVE_FDOT2 1
#endif
#endif

__device__ __forceinline__ float dot2acc(uint32_t w, uint32_t x, float acc) {
#ifdef HAVE_FDOT2
    return __builtin_amdgcn_fdot2(__builtin_bit_cast(half2v, w),
                                  __builtin_bit_cast(half2v, x), acc, false);
#else
    half2v hw = __builtin_bit_cast(half2v, w);
    half2v hx = __builtin_bit_cast(half2v, x);
    return acc + (float)hw.x * (float)hx.x + (float)hw.y * (float)hx.y;
#endif
}

#define ALOAD(p)      __hip_atomic_load((p), __ATOMIC_RELAXED, __HIP_MEMORY_SCOPE_AGENT)
#define ASTORE(p, v)  __hip_atomic_store((p), (v), __ATOMIC_RELAXED, __HIP_MEMORY_SCOPE_AGENT)

// ---- workspace layout ----
constexpr size_t X0_DW   = (size_t)S_LEN * (DIN0 / 2);            // 4 MB
constexpr size_t X0B     = X0_DW * 4;
constexpr size_t RING_DW = (size_t)NL * RING * HID;               // tagged dwords, 2 MB
constexpr size_t RINGB   = RING_DW * 4;
constexpr size_t WK_DW   = (size_t)NWAVE * SP * 64;               // 65536 dw per block
constexpr size_t WL_DW   = (size_t)NCU_L * WK_DW;
constexpr size_t WB      = (size_t)NL * WL_DW * 4;                // ~67 MB
constexpr size_t FLAG_N  = (size_t)NL * NCU_L + 1;                // prog[4][64] + abort
constexpr size_t TOTAL_WS = X0B + RINGB + WB + FLAG_N * 4;

// ---------------- pre-kernels ----------------

__global__ void conv_x_kernel(const float* __restrict__ x, uint32_t* __restrict__ dst) {
    int i = blockIdx.x * 256 + threadIdx.x;   // exactly X0_DW threads
    float v0 = x[2 * i], v1 = x[2 * i + 1];
    half2v h = {(_Float16)v0, (_Float16)v1};
    dst[i] = __builtin_bit_cast(uint32_t, h);
}

// dst layout: [k(64)][wave(8)][c4(32)][lane(64)][e(4)].
// Column space (halves): [0,1024) = x region (cols >= din zero-padded),
//                        [1024,2048) = h region.
__global__ void pack_weights_kernel(const float* __restrict__ wih, const float* __restrict__ whh,
                                    int din, uint32_t* __restrict__ dst) {
    int i = blockIdx.x * 256 + threadIdx.x;   // exactly WL_DW threads
    int e = i & 3;  int q = i >> 2;
    int l = q & 63; q >>= 6;
    int c4 = q & 31; q >>= 5;
    int w = q & 7;  int k = q >> 3;
    int c = 4 * c4 + e;
    int col = w * 256 + 2 * c;                // half col in [0,2048)
    int row = (l >> 4) * HID + k * 16 + (l & 15);
    float v0, v1;
    {
        int hc = col;
        v0 = (hc < 1024) ? ((hc < din) ? wih[(size_t)row * din + hc] : 0.f)
                         : whh[(size_t)row * HID + (hc - 1024)];
        hc = col + 1;
        v1 = (hc < 1024) ? ((hc < din) ? wih[(size_t)row * din + hc] : 0.f)
                         : whh[(size_t)row * HID + (hc - 1024)];
    }
    half2v h = {(_Float16)v0, (_Float16)v1};
    dst[i] = __builtin_bit_cast(uint32_t, h);
}

__global__ void init_misc_kernel(int* __restrict__ flags, int n, float* __restrict__ out,
                                 const float* __restrict__ fcb) {
    int i = blockIdx.x * 256 + threadIdx.x;
    if (i < n) flags[i] = 0;
    if (i == 0) out[0] = fcb[0];
}

// ---------------- persistent LSTM kernel ----------------

__device__ __forceinline__ float frcp_f(float x) { return __builtin_amdgcn_rcpf(x); }
__device__ __forceinline__ float fsigmoid(float x) { return frcp_f(1.f + __expf(-x)); }
__device__ __forceinline__ float ftanh_c(float x) {
    float e = __expf(-2.f * x);
    return (1.f - e) * frcp_f(1.f + e);
}

__device__ __forceinline__ uint32_t tagbad(const v4u& d, uint32_t tag) {
    return ((d[0] ^ tag) | (d[1] ^ tag) | (d[2] ^ tag) | (d[3] ^ tag)) & 0xFFFFu;
}

// Poll 4 consecutive tagged dwords until all carry `tag` in low 16 bits.
// 2-deep pipelined: two sc0sc1 loads in flight, s_waitcnt vmcnt(1) retires
// the older -> sampling period ~ half the MALL round trip. EVERY waitcnt asm
// is followed by sched_barrier(0) so the compiler cannot hoist the tag-check
// VALU above it (rule #18 -- R11's 8x regression).
__device__ __forceinline__ v4u poll4(const uint32_t* p, uint32_t tag, int* abortf) {
    v4u d0, d1;
    int tries = 0;
    asm volatile("global_load_dwordx4 %0, %2, off sc0 sc1\n\t"
                 "global_load_dwordx4 %1, %2, off sc0 sc1"
                 : "=v"(d0), "=v"(d1) : "v"(p) : "memory");
    for (;;) {
        asm volatile("s_waitcnt vmcnt(1)" ::: "memory");          // d0 ready
        __builtin_amdgcn_sched_barrier(0);
        if (tagbad(d0, tag) == 0) {
            asm volatile("s_waitcnt vmcnt(0)" ::: "memory");      // drain d1
            __builtin_amdgcn_sched_barrier(0);
            return d0;
        }
        asm volatile("global_load_dwordx4 %0, %1, off sc0 sc1"    // reissue d0
                     : "=v"(d0) : "v"(p) : "memory");
        asm volatile("s_waitcnt vmcnt(1)" ::: "memory");          // d1 ready
        __builtin_amdgcn_sched_barrier(0);
        if (tagbad(d1, tag) == 0) {
            asm volatile("s_waitcnt vmcnt(0)" ::: "memory");      // drain d0
            __builtin_amdgcn_sched_barrier(0);
            return d1;
        }
        if ((++tries & 127) == 0) {
            // rare path: drain, check abort, restore 2-deep invariant
            asm volatile("s_waitcnt vmcnt(0)" ::: "memory");
            __builtin_amdgcn_sched_barrier(0);
            if (ALOAD(abortf)) return d1;
            if (tries > (1 << 21)) { ASTORE(abortf, 1); return d1; }
            asm volatile("global_load_dwordx4 %0, %2, off sc0 sc1\n\t"
                         "global_load_dwordx4 %1, %2, off sc0 sc1"
                         : "=v"(d0), "=v"(d1) : "v"(p) : "memory");
            continue;
        }
        asm volatile("global_load_dwordx4 %0, %1, off sc0 sc1"    // reissue d1
                     : "=v"(d1) : "v"(p) : "memory");
    }
}

#define REP32(M) M(0) M(1) M(2) M(3) M(4) M(5) M(6) M(7) M(8) M(9) M(10) M(11) \
                 M(12) M(13) M(14) M(15) M(16) M(17) M(18) M(19) M(20) M(21) M(22) M(23) \
                 M(24) M(25) M(26) M(27) M(28) M(29) M(30) M(31)

__device__ __forceinline__ void run_layer(
    int k, bool isL0,
    const uint32_t* __restrict__ x0p,     // layer 0 input (packed halves, untagged)
    const uint32_t* up_ring,              // upstream tagged ring (null for L0)
    uint32_t* own_ring,                   // own tagged ring
    const uint32_t* __restrict__ wsrc,
    const float* __restrict__ bias,
    const float* __restrict__ fcw,
    float* out,
    int* prog_own, int* prog_dn, int* abortf, bool doFC)
{
    __shared__ alignas(16) uint32_t in_lds[NWAVE * SP];   // 1024 dw = 4 KB
    __shared__ float red[NWAVE][65];                      // +1 pad vs bank aliasing

    const int tid  = threadIdx.x;
    const int wave = tid >> 6;
    const int lane = tid & 63;

    // ---- weight slice: 32 v4u via asm loads (non-remat); waves_per_eu(2,2)
    //      gives the 256-VGPR budget they need to stay resident.
    const uint32_t* wb = wsrc + (size_t)wave * (SP * 64) + lane * 4;
#define WLOAD(i) v4u W##i; { const uint32_t* a_ = wb + (size_t)(i) * 256;        \
        asm volatile("global_load_dwordx4 %0, %1, off\n\ts_waitcnt vmcnt(0)"     \
                     : "=v"(W##i) : "v"(a_) : "memory"); }
    REP32(WLOAD)
#undef WLOAD

    // Epilogue mapping (wave 0 only): lane l holds gate-row l of this block:
    // gate = l>>4 (i,f,g,o), h-index j = l&15. Lanes 0-15 finalize h_j.
    const float bval = (wave == 0)
        ? bias[(lane >> 4) * HID + k * 16 + (lane & 15)] : 0.f;
    float fcv = 0.f;
    if (doFC && wave == 0 && lane < 16) fcv = fcw[k * 16 + lane];
    float cst = 0.f, hval = 0.f;

    for (int t = 0; t < S_LEN; ++t) {
        const int slot = t & RMASK;

        // ---- ring-overrun guard (every 32 steps; wave 1, off wave-0 path) ----
        // Producer will overwrite slots t..t+31 (= x_{t-128}..x_{t-97});
        // require downstream progress >= t-96 before proceeding. The staging
        // barrier orders this before wave 0's store of slot t.
        if (prog_dn && wave == 1 && t >= RING && (t & 31) == 0) {
            int it = 0;
            for (;;) {
                int ok = (ALOAD(prog_dn + lane) >= t - RING + 32);
                if (__all(ok)) break;
                if ((++it & 255) == 0) {
                    if (ALOAD(abortf)) break;
                    if (it > (1 << 22)) { ASTORE(abortf, 1); break; }
                }
            }
        }

        // ---- stage [x(512dw) | h_{t-1}(512dw)] into LDS via tagged polls ----
        {
            uint32_t dw0, dw1;
            if (tid < 256) {
                if (isL0) {
                    uint64_t v = 0;
                    if (tid < 64) v = *(const uint64_t*)(x0p + (size_t)t * 128 + 2 * tid);
                    dw0 = (uint32_t)v; dw1 = (uint32_t)(v >> 32);
                } else {
                    v4u d = poll4(up_ring + (size_t)slot * HID + 4 * tid, (uint32_t)t, abortf);
                    dw0 = (d[0] >> 16) | (d[1] & 0xFFFF0000u);
                    dw1 = (d[2] >> 16) | (d[3] & 0xFFFF0000u);
                }
            } else {
                if (t) {
                    v4u d = poll4(own_ring + (size_t)((t - 1) & RMASK) * HID + 4 * (tid - 256),
                                  (uint32_t)(t - 1), abortf);
                    dw0 = (d[0] >> 16) | (d[1] & 0xFFFF0000u);
                    dw1 = (d[2] >> 16) | (d[3] & 0xFFFF0000u);
                } else { dw0 = 0u; dw1 = 0u; }
            }
            in_lds[2 * tid] = dw0;
            in_lds[2 * tid + 1] = dw1;
        }
        __syncthreads();

        // ---- dot: lane = gate row, wave = 256-half column slice ----
        const uint32_t* wi = in_lds + wave * SP;
        float a0 = 0, a1 = 0, a2 = 0, a3 = 0;
#define DOT(i) { v4u x_ = *(const v4u*)&wi[4 * (i)];            \
        a0 = dot2acc(W##i[0], x_[0], a0);                       \
        a1 = dot2acc(W##i[1], x_[1], a1);                       \
        a2 = dot2acc(W##i[2], x_[2], a2);                       \
        a3 = dot2acc(W##i[3], x_[3], a3); }
        DOT(0) DOT(1) DOT(2) DOT(3)
        __builtin_amdgcn_sched_barrier(0);
        DOT(4) DOT(5) DOT(6) DOT(7)
        __builtin_amdgcn_sched_barrier(0);
        DOT(8) DOT(9) DOT(10) DOT(11)
        __builtin_amdgcn_sched_barrier(0);
        DOT(12) DOT(13) DOT(14) DOT(15)
        __builtin_amdgcn_sched_barrier(0);
        DOT(16) DOT(17) DOT(18) DOT(19)
        __builtin_amdgcn_sched_barrier(0);
        DOT(20) DOT(21) DOT(22) DOT(23)
        __builtin_amdgcn_sched_barrier(0);
        DOT(24) DOT(25) DOT(26) DOT(27)
        __builtin_amdgcn_sched_barrier(0);
        DOT(28) DOT(29) DOT(30) DOT(31)
#undef DOT
        red[wave][lane] = (a0 + a1) + (a2 + a3);
        __syncthreads();

        // ---- wave-0-only epilogue: gates + coalesced 64B h-publish ----
        // Other waves fall through and start polling step t+1 immediately;
        // they cannot pass the next staging barrier until wave 0 arrives, so
        // red[] of this step is not overwritten while wave 0 reads it.
        if (wave == 0) {
            float p = red[0][lane];
#pragma unroll
            for (int w = 1; w < NWAVE; ++w) p += red[w][lane];
            p += bval;
            p = fminf(15.f, fmaxf(-15.f, p));
            float pf = __shfl_xor(p, 16);
            float pg = __shfl_xor(p, 32);
            float po = __shfl_xor(p, 48);
            uint32_t dtag = 0;
            if (lane < 16) {
                float ig = fsigmoid(p);
                float fg = fsigmoid(pf);
                float gg = ftanh_c(pg);
                float og = fsigmoid(po);
                cst = fg * cst + ig * gg;
                float c2 = fminf(15.f, fmaxf(-15.f, cst));
                hval = og * ftanh_c(c2);
                uint32_t hb = (uint32_t)__builtin_bit_cast(unsigned short, (_Float16)hval);
                dtag = (hb << 16) | ((uint32_t)t & 0xFFFFu);
            }
            // pack 16 tagged dwords into lanes 0-3 (4 each) and store 64B
            // as 4 coalesced dwordx4 -> ~one MALL transaction.
            int src = (lane << 2) & 63;
            uint32_t e0 = __shfl(dtag, src);
            uint32_t e1 = __shfl(dtag, src + 1);
            uint32_t e2 = __shfl(dtag, src + 2);
            uint32_t e3 = __shfl(dtag, src + 3);
            if (lane < 4) {
                v4u v; v[0] = e0; v[1] = e1; v[2] = e2; v[3] = e3;
                const uint32_t* addr = own_ring + (size_t)slot * HID + k * 16 + 4 * lane;
                asm volatile("global_store_dwordx4 %0, %1, off sc0 sc1"
                             :: "v"(addr), "v"(v) : "memory");
            }
            if (((t & 31) == 31) && lane == 0) ASTORE(prog_own + k, t);
        }
    }

    // ---- final FC (layer 3): y = fc_w . h_last + fc_b ----
    if (doFC && wave == 0) {
        float p = (lane < 16) ? fcv * hval : 0.f;
        p += __shfl_xor(p, 1);
        p += __shfl_xor(p, 2);
        p += __shfl_xor(p, 4);
        p += __shfl_xor(p, 8);
        if (lane == 0) atomicAdd(out, p);
    }
}

__global__ __launch_bounds__(NTHR, 2) __attribute__((amdgpu_waves_per_eu(2, 2)))
void lstm_persistent(
    const uint32_t* __restrict__ x0p,
    uint32_t* ring,
    const uint32_t* __restrict__ wp,
    const float* __restrict__ b0, const float* __restrict__ b1,
    const float* __restrict__ b2, const float* __restrict__ b3,
    const float* __restrict__ fcw, float* out,
    int* flags, int* abortf)
{
    const int bid = blockIdx.x;
    const int xcd = bid & 7;
    const int layer = xcd >> 1;                    // 2 XCDs per layer
    const int k = ((bid >> 3) << 1) | (xcd & 1);   // 0..63 within layer

    const float* bias = (layer == 0) ? b0 : (layer == 1) ? b1 : (layer == 2) ? b2 : b3;
    int* prog_own = flags + layer * NCU_L;
    int* prog_dn  = (layer < 3) ? (flags + (layer + 1) * NCU_L) : nullptr;

    uint32_t* own_ring = ring + (size_t)layer * RING * HID;
    const uint32_t* up_ring = layer ? (ring + (size_t)(layer - 1) * RING * HID) : nullptr;
    const uint32_t* wsrc = wp + (size_t)layer * WL_DW + (size_t)k * WK_DW;

    run_layer(k, layer == 0, x0p, up_ring, own_ring, wsrc, bias, fcw, out,
              prog_own, prog_dn, abortf, layer == 3);
}

// ---------------- host launcher ----------------

extern "C" void kernel_launch(void* const* d_in, const int* in_sizes, int n_in,
                              void* d_out, int out_size, void* d_ws, size_t ws_size,
                              hipStream_t stream) {
    const float* seq  = (const float*)d_in[0];
    const float* wih0 = (const float*)d_in[1];
    const float* whh0 = (const float*)d_in[2];
    const float* b0   = (const float*)d_in[3];
    const float* wih1 = (const float*)d_in[4];
    const float* whh1 = (const float*)d_in[5];
    const float* b1   = (const float*)d_in[6];
    const float* wih2 = (const float*)d_in[7];
    const float* whh2 = (const float*)d_in[8];
    const float* b2   = (const float*)d_in[9];
    const float* wih3 = (const float*)d_in[10];
    const float* whh3 = (const float*)d_in[11];
    const float* b3   = (const float*)d_in[12];
    const float* fcw  = (const float*)d_in[13];
    const float* fcb  = (const float*)d_in[14];
    float* out = (float*)d_out;

    if (ws_size < TOTAL_WS) return;

    uint8_t* ws = (uint8_t*)d_ws;
    uint32_t* x0p  = (uint32_t*)ws;
    uint32_t* ring = (uint32_t*)(ws + X0B);
    uint32_t* wp   = (uint32_t*)(ws + X0B + RINGB);
    int* flags     = (int*)(ws + X0B + RINGB + WB);
    int* abortf    = flags + NL * NCU_L;

    conv_x_kernel<<<(int)(X0_DW / 256), 256, 0, stream>>>(seq, x0p);
    pack_weights_kernel<<<(int)(WL_DW / 256), 256, 0, stream>>>(wih0, whh0, DIN0, wp);
    pack_weights_kernel<<<(int)(WL_DW / 256), 256, 0, stream>>>(wih1, whh1, HID, wp + WL_DW);
    pack_weights_kernel<<<(int)(WL_DW / 256), 256, 0, stream>>>(wih2, whh2, HID, wp + 2 * WL_DW);
    pack_weights_kernel<<<(int)(WL_DW / 256), 256, 0, stream>>>(wih3, whh3, HID, wp + 3 * WL_DW);
    init_misc_kernel<<<(int)((FLAG_N + 255) / 256), 256, 0, stream>>>(flags, (int)FLAG_N, out, fcb);

    lstm_persistent<<<256, NTHR, 0, stream>>>(x0p, ring, wp, b0, b1, b2, b3, fcw, out, flags, abortf);
}

// Round 7
// 16532.408 us; speedup vs baseline: 10.0707x; 10.0707x over previous
//
#include <hip/hip_runtime.h>
#include <stdint.h>

// R14: R12 base (coalesced h-publish, 17.53ms) + publish-chain trims.
//  - Lanes 0-15 store their tagged h dword DIRECTLY (one wave instruction,
//    16 contiguous dwords = one 64B transaction) -- removes the 4 pack
//    shuffles (~80cy) from the serial publish path.
//  - s_setprio(1) around the wave-0 epilogue: 7 sibling waves are spamming
//    the CU's VMEM pipe with next-step polls; prioritize the serial chain.
//  - Pairwise-tree reduce of the 8 wave partials.
// Pipelined polls (R11/R13) are blacklisted: 2-deep same-address poll loads
// regress ~9x even with sched_barrier(0) fences (hardware-level merge /
// queue-feedback suspected). Serial load->vmcnt(0)->check is the floor.

#define S_LEN 8192
#define HID   1024
#define DIN0  256
#define NL    4
#define NCU_L 64
#define NTHR  512
#define NWAVE 8
#define SP    128          // weight dwords per lane per wave
#define RING  128
#define RMASK (RING - 1)

typedef _Float16 half2v __attribute__((ext_vector_type(2)));
typedef uint32_t v4u   __attribute__((ext_vector_type(4)));

#if defined(__has_builtin)
#if __has_builtin(__builtin_amdgcn_fdot2)
#define HAVE_FDOT2 1
#endif
#endif

__device__ __forceinline__ float dot2acc(uint32_t w, uint32_t x, float acc) {
#ifdef HAVE_FDOT2
    return __builtin_amdgcn_fdot2(__builtin_bit_cast(half2v, w),
                                  __builtin_bit_cast(half2v, x), acc, false);
#else
    half2v hw = __builtin_bit_cast(half2v, w);
    half2v hx = __builtin_bit_cast(half2v, x);
    return acc + (float)hw.x * (float)hx.x + (float)hw.y * (float)hx.y;
#endif
}

#define ALOAD(p)      __hip_atomic_load((p), __ATOMIC_RELAXED, __HIP_MEMORY_SCOPE_AGENT)
#define ASTORE(p, v)  __hip_atomic_store((p), (v), __ATOMIC_RELAXED, __HIP_MEMORY_SCOPE_AGENT)

// ---- workspace layout ----
constexpr size_t X0_DW   = (size_t)S_LEN * (DIN0 / 2);            // 4 MB
constexpr size_t X0B     = X0_DW * 4;
constexpr size_t RING_DW = (size_t)NL * RING * HID;               // tagged dwords, 2 MB
constexpr size_t RINGB   = RING_DW * 4;
constexpr size_t WK_DW   = (size_t)NWAVE * SP * 64;               // 65536 dw per block
constexpr size_t WL_DW   = (size_t)NCU_L * WK_DW;
constexpr size_t WB      = (size_t)NL * WL_DW * 4;                // ~67 MB
constexpr size_t FLAG_N  = (size_t)NL * NCU_L + 1;                // prog[4][64] + abort
constexpr size_t TOTAL_WS = X0B + RINGB + WB + FLAG_N * 4;

// ---------------- pre-kernels ----------------

__global__ void conv_x_kernel(const float* __restrict__ x, uint32_t* __restrict__ dst) {
    int i = blockIdx.x * 256 + threadIdx.x;   // exactly X0_DW threads
    float v0 = x[2 * i], v1 = x[2 * i + 1];
    half2v h = {(_Float16)v0, (_Float16)v1};
    dst[i] = __builtin_bit_cast(uint32_t, h);
}

// dst layout: [k(64)][wave(8)][c4(32)][lane(64)][e(4)].
// Column space (halves): [0,1024) = x region (cols >= din zero-padded),
//                        [1024,2048) = h region.
__global__ void pack_weights_kernel(const float* __restrict__ wih, const float* __restrict__ whh,
                                    int din, uint32_t* __restrict__ dst) {
    int i = blockIdx.x * 256 + threadIdx.x;   // exactly WL_DW threads
    int e = i & 3;  int q = i >> 2;
    int l = q & 63; q >>= 6;
    int c4 = q & 31; q >>= 5;
    int w = q & 7;  int k = q >> 3;
    int c = 4 * c4 + e;
    int col = w * 256 + 2 * c;                // half col in [0,2048)
    int row = (l >> 4) * HID + k * 16 + (l & 15);
    float v0, v1;
    {
        int hc = col;
        v0 = (hc < 1024) ? ((hc < din) ? wih[(size_t)row * din + hc] : 0.f)
                         : whh[(size_t)row * HID + (hc - 1024)];
        hc = col + 1;
        v1 = (hc < 1024) ? ((hc < din) ? wih[(size_t)row * din + hc] : 0.f)
                         : whh[(size_t)row * HID + (hc - 1024)];
    }
    half2v h = {(_Float16)v0, (_Float16)v1};
    dst[i] = __builtin_bit_cast(uint32_t, h);
}

__global__ void init_misc_kernel(int* __restrict__ flags, int n, float* __restrict__ out,
                                 const float* __restrict__ fcb) {
    int i = blockIdx.x * 256 + threadIdx.x;
    if (i < n) flags[i] = 0;
    if (i == 0) out[0] = fcb[0];
}

// ---------------- persistent LSTM kernel ----------------

__device__ __forceinline__ float frcp_f(float x) { return __builtin_amdgcn_rcpf(x); }
__device__ __forceinline__ float fsigmoid(float x) { return frcp_f(1.f + __expf(-x)); }
__device__ __forceinline__ float ftanh_c(float x) {
    float e = __expf(-2.f * x);
    return (1.f - e) * frcp_f(1.f + e);
}

// Poll 4 consecutive tagged dwords until all carry `tag` in low 16 bits.
// Single 16B load (sc0 sc1 = bypass caches to the coherence point) per
// iteration; each dword carries its own tag, all 4 must match. Proven R10/R12
// form; pipelined variants (R11/R13) are blacklisted (~9x regressions).
__device__ __forceinline__ v4u poll4(const uint32_t* p, uint32_t tag, int* abortf) {
    v4u d;
    int tries = 0;
    for (;;) {
        asm volatile("global_load_dwordx4 %0, %1, off sc0 sc1\n\ts_waitcnt vmcnt(0)"
                     : "=v"(d) : "v"(p) : "memory");
        uint32_t bad = ((d[0] ^ tag) | (d[1] ^ tag) | (d[2] ^ tag) | (d[3] ^ tag)) & 0xFFFFu;
        if (bad == 0) break;
        if ((++tries & 255) == 0) {
            if (ALOAD(abortf)) break;
            if (tries > (1 << 22)) { ASTORE(abortf, 1); break; }
        }
    }
    return d;
}

#define REP32(M) M(0) M(1) M(2) M(3) M(4) M(5) M(6) M(7) M(8) M(9) M(10) M(11) \
                 M(12) M(13) M(14) M(15) M(16) M(17) M(18) M(19) M(20) M(21) M(22) M(23) \
                 M(24) M(25) M(26) M(27) M(28) M(29) M(30) M(31)

__device__ __forceinline__ void run_layer(
    int k, bool isL0,
    const uint32_t* __restrict__ x0p,     // layer 0 input (packed halves, untagged)
    const uint32_t* up_ring,              // upstream tagged ring (null for L0)
    uint32_t* own_ring,                   // own tagged ring
    const uint32_t* __restrict__ wsrc,
    const float* __restrict__ bias,
    const float* __restrict__ fcw,
    float* out,
    int* prog_own, int* prog_dn, int* abortf, bool doFC)
{
    __shared__ alignas(16) uint32_t in_lds[NWAVE * SP];   // 1024 dw = 4 KB
    __shared__ float red[NWAVE][65];                      // +1 pad vs bank aliasing

    const int tid  = threadIdx.x;
    const int wave = tid >> 6;
    const int lane = tid & 63;

    // ---- weight slice: 32 v4u via asm loads (non-remat); waves_per_eu(2,2)
    //      gives the 256-VGPR budget they need to stay resident.
    const uint32_t* wb = wsrc + (size_t)wave * (SP * 64) + lane * 4;
#define WLOAD(i) v4u W##i; { const uint32_t* a_ = wb + (size_t)(i) * 256;        \
        asm volatile("global_load_dwordx4 %0, %1, off\n\ts_waitcnt vmcnt(0)"     \
                     : "=v"(W##i) : "v"(a_) : "memory"); }
    REP32(WLOAD)
#undef WLOAD

    // Epilogue mapping (wave 0 only): lane l holds gate-row l of this block:
    // gate = l>>4 (i,f,g,o), h-index j = l&15. Lanes 0-15 finalize h_j.
    const float bval = (wave == 0)
        ? bias[(lane >> 4) * HID + k * 16 + (lane & 15)] : 0.f;
    float fcv = 0.f;
    if (doFC && wave == 0 && lane < 16) fcv = fcw[k * 16 + lane];
    float cst = 0.f, hval = 0.f;

    for (int t = 0; t < S_LEN; ++t) {
        const int slot = t & RMASK;

        // ---- ring-overrun guard (every 32 steps; wave 1, off wave-0 path) ----
        // Producer will overwrite slots t..t+31 (= x_{t-128}..x_{t-97});
        // require downstream progress >= t-96 before proceeding. The staging
        // barrier orders this before wave 0's store of slot t.
        if (prog_dn && wave == 1 && t >= RING && (t & 31) == 0) {
            int it = 0;
            for (;;) {
                int ok = (ALOAD(prog_dn + lane) >= t - RING + 32);
                if (__all(ok)) break;
                if ((++it & 255) == 0) {
                    if (ALOAD(abortf)) break;
                    if (it > (1 << 22)) { ASTORE(abortf, 1); break; }
                }
            }
        }

        // ---- stage [x(512dw) | h_{t-1}(512dw)] into LDS via tagged polls ----
        {
            uint32_t dw0, dw1;
            if (tid < 256) {
                if (isL0) {
                    uint64_t v = 0;
                    if (tid < 64) v = *(const uint64_t*)(x0p + (size_t)t * 128 + 2 * tid);
                    dw0 = (uint32_t)v; dw1 = (uint32_t)(v >> 32);
                } else {
                    v4u d = poll4(up_ring + (size_t)slot * HID + 4 * tid, (uint32_t)t, abortf);
                    dw0 = (d[0] >> 16) | (d[1] & 0xFFFF0000u);
                    dw1 = (d[2] >> 16) | (d[3] & 0xFFFF0000u);
                }
            } else {
                if (t) {
                    v4u d = poll4(own_ring + (size_t)((t - 1) & RMASK) * HID + 4 * (tid - 256),
                                  (uint32_t)(t - 1), abortf);
                    dw0 = (d[0] >> 16) | (d[1] & 0xFFFF0000u);
                    dw1 = (d[2] >> 16) | (d[3] & 0xFFFF0000u);
                } else { dw0 = 0u; dw1 = 0u; }
            }
            in_lds[2 * tid] = dw0;
            in_lds[2 * tid + 1] = dw1;
        }
        __syncthreads();

        // ---- dot: lane = gate row, wave = 256-half column slice ----
        const uint32_t* wi = in_lds + wave * SP;
        float a0 = 0, a1 = 0, a2 = 0, a3 = 0;
#define DOT(i) { v4u x_ = *(const v4u*)&wi[4 * (i)];            \
        a0 = dot2acc(W##i[0], x_[0], a0);                       \
        a1 = dot2acc(W##i[1], x_[1], a1);                       \
        a2 = dot2acc(W##i[2], x_[2], a2);                       \
        a3 = dot2acc(W##i[3], x_[3], a3); }
        DOT(0) DOT(1) DOT(2) DOT(3)
        __builtin_amdgcn_sched_barrier(0);
        DOT(4) DOT(5) DOT(6) DOT(7)
        __builtin_amdgcn_sched_barrier(0);
        DOT(8) DOT(9) DOT(10) DOT(11)
        __builtin_amdgcn_sched_barrier(0);
        DOT(12) DOT(13) DOT(14) DOT(15)
        __builtin_amdgcn_sched_barrier(0);
        DOT(16) DOT(17) DOT(18) DOT(19)
        __builtin_amdgcn_sched_barrier(0);
        DOT(20) DOT(21) DOT(22) DOT(23)
        __builtin_amdgcn_sched_barrier(0);
        DOT(24) DOT(25) DOT(26) DOT(27)
        __builtin_amdgcn_sched_barrier(0);
        DOT(28) DOT(29) DOT(30) DOT(31)
#undef DOT
        red[wave][lane] = (a0 + a1) + (a2 + a3);
        __syncthreads();

        // ---- wave-0-only epilogue: gates + coalesced 64B h-publish ----
        // Other waves fall through and start polling step t+1 immediately;
        // they cannot pass the next staging barrier until wave 0 arrives, so
        // red[] of this step is not overwritten while wave 0 reads it.
        if (wave == 0) {
            __builtin_amdgcn_s_setprio(1);
            float r0 = red[0][lane], r1 = red[1][lane];
            float r2 = red[2][lane], r3 = red[3][lane];
            float r4 = red[4][lane], r5 = red[5][lane];
            float r6 = red[6][lane], r7 = red[7][lane];
            float p = ((r0 + r1) + (r2 + r3)) + ((r4 + r5) + (r6 + r7));
            p += bval;
            p = fminf(15.f, fmaxf(-15.f, p));
            float pf = __shfl_xor(p, 16);
            float pg = __shfl_xor(p, 32);
            float po = __shfl_xor(p, 48);
            if (lane < 16) {
                float ig = fsigmoid(p);
                float fg = fsigmoid(pf);
                float gg = ftanh_c(pg);
                float og = fsigmoid(po);
                cst = fg * cst + ig * gg;
                float c2 = fminf(15.f, fmaxf(-15.f, cst));
                hval = og * ftanh_c(c2);
                uint32_t hb = (uint32_t)__builtin_bit_cast(unsigned short, (_Float16)hval);
                uint32_t dtag = (hb << 16) | ((uint32_t)t & 0xFFFFu);
                // one wave instruction, 16 contiguous dwords -> one 64B
                // coalesced agent-scope transaction (same as R12's 4x dwordx4,
                // minus the 4 pack shuffles on the serial path).
                ASTORE(own_ring + (size_t)slot * HID + k * 16 + lane, dtag);
            }
            __builtin_amdgcn_s_setprio(0);
            if (((t & 31) == 31) && lane == 0) ASTORE(prog_own + k, t);
        }
    }

    // ---- final FC (layer 3): y = fc_w . h_last + fc_b ----
    if (doFC && wave == 0) {
        float p = (lane < 16) ? fcv * hval : 0.f;
        p += __shfl_xor(p, 1);
        p += __shfl_xor(p, 2);
        p += __shfl_xor(p, 4);
        p += __shfl_xor(p, 8);
        if (lane == 0) atomicAdd(out, p);
    }
}

__global__ __launch_bounds__(NTHR, 2) __attribute__((amdgpu_waves_per_eu(2, 2)))
void lstm_persistent(
    const uint32_t* __restrict__ x0p,
    uint32_t* ring,
    const uint32_t* __restrict__ wp,
    const float* __restrict__ b0, const float* __restrict__ b1,
    const float* __restrict__ b2, const float* __restrict__ b3,
    const float* __restrict__ fcw, float* out,
    int* flags, int* abortf)
{
    const int bid = blockIdx.x;
    const int xcd = bid & 7;
    const int layer = xcd >> 1;                    // 2 XCDs per layer
    const int k = ((bid >> 3) << 1) | (xcd & 1);   // 0..63 within layer

    const float* bias = (layer == 0) ? b0 : (layer == 1) ? b1 : (layer == 2) ? b2 : b3;
    int* prog_own = flags + layer * NCU_L;
    int* prog_dn  = (layer < 3) ? (flags + (layer + 1) * NCU_L) : nullptr;

    uint32_t* own_ring = ring + (size_t)layer * RING * HID;
    const uint32_t* up_ring = layer ? (ring + (size_t)(layer - 1) * RING * HID) : nullptr;
    const uint32_t* wsrc = wp + (size_t)layer * WL_DW + (size_t)k * WK_DW;

    run_layer(k, layer == 0, x0p, up_ring, own_ring, wsrc, bias, fcw, out,
              prog_own, prog_dn, abortf, layer == 3);
}

// ---------------- host launcher ----------------

extern "C" void kernel_launch(void* const* d_in, const int* in_sizes, int n_in,
                              void* d_out, int out_size, void* d_ws, size_t ws_size,
                              hipStream_t stream) {
    const float* seq  = (const float*)d_in[0];
    const float* wih0 = (const float*)d_in[1];
    const float* whh0 = (const float*)d_in[2];
    const float* b0   = (const float*)d_in[3];
    const float* wih1 = (const float*)d_in[4];
    const float* whh1 = (const float*)d_in[5];
    const float* b1   = (const float*)d_in[6];
    const float* wih2 = (const float*)d_in[7];
    const float* whh2 = (const float*)d_in[8];
    const float* b2   = (const float*)d_in[9];
    const float* wih3 = (const float*)d_in[10];
    const float* whh3 = (const float*)d_in[11];
    const float* b3   = (const float*)d_in[12];
    const float* fcw  = (const float*)d_in[13];
    const float* fcb  = (const float*)d_in[14];
    float* out = (float*)d_out;

    if (ws_size < TOTAL_WS) return;

    uint8_t* ws = (uint8_t*)d_ws;
    uint32_t* x0p  = (uint32_t*)ws;
    uint32_t* ring = (uint32_t*)(ws + X0B);
    uint32_t* wp   = (uint32_t*)(ws + X0B + RINGB);
    int* flags     = (int*)(ws + X0B + RINGB + WB);
    int* abortf    = flags + NL * NCU_L;

    conv_x_kernel<<<(int)(X0_DW / 256), 256, 0, stream>>>(seq, x0p);
    pack_weights_kernel<<<(int)(WL_DW / 256), 256, 0, stream>>>(wih0, whh0, DIN0, wp);
    pack_weights_kernel<<<(int)(WL_DW / 256), 256, 0, stream>>>(wih1, whh1, HID, wp + WL_DW);
    pack_weights_kernel<<<(int)(WL_DW / 256), 256, 0, stream>>>(wih2, whh2, HID, wp + 2 * WL_DW);
    pack_weights_kernel<<<(int)(WL_DW / 256), 256, 0, stream>>>(wih3, whh3, HID, wp + 3 * WL_DW);
    init_misc_kernel<<<(int)((FLAG_N + 255) / 256), 256, 0, stream>>>(flags, (int)FLAG_N, out, fcb);

    lstm_persistent<<<256, NTHR, 0, stream>>>(x0p, ring, wp, b0, b1, b2, b3, fcw, out, flags, abortf);
}

// Round 8
// 15647.478 us; speedup vs baseline: 10.6403x; 1.0566x over previous
//
#include <hip/hip_runtime.h>
#include <stdint.h>

// R15: R14 base (16.53ms) + single-barrier step.
//  - barrier1 (post-staging) REMOVED: in_lds is wave-private (each wave stages
//    and dots only its own 128-dword slice), so the barrier ordered nothing.
//    Benefit: each wave's dots start at ITS OWN detect (not max over waves),
//    and x-waves (0-3, data ready early) dot while their SIMD-paired h-waves
//    (4-7) still spin -> h-dots issue nearly uncontended after detect.
//  - red double-buffered red[t&1]: race-free through the single barrier
//    (write of parity b at step t+2 is after barrier2(t+1), which is after
//    wave0's read of parity b at step t).
//  - Epilogue: all 64 lanes compute their own gate transform (lanes 32-47
//    tanh, others sigmoid) in parallel, THEN 3 shuffles gather -> shorter
//    serial chain for lanes 0-15.
// Publish (16-lane coalesced tagged store), poll4, guard: unchanged.

#define S_LEN 8192
#define HID   1024
#define DIN0  256
#define NL    4
#define NCU_L 64
#define NTHR  512
#define NWAVE 8
#define SP    128          // weight dwords per lane per wave
#define RING  128
#define RMASK (RING - 1)

typedef _Float16 half2v __attribute__((ext_vector_type(2)));
typedef uint32_t v4u   __attribute__((ext_vector_type(4)));

#if defined(__has_builtin)
#if __has_builtin(__builtin_amdgcn_fdot2)
#define HAVE_FDOT2 1
#endif
#endif

__device__ __forceinline__ float dot2acc(uint32_t w, uint32_t x, float acc) {
#ifdef HAVE_FDOT2
    return __builtin_amdgcn_fdot2(__builtin_bit_cast(half2v, w),
                                  __builtin_bit_cast(half2v, x), acc, false);
#else
    half2v hw = __builtin_bit_cast(half2v, w);
    half2v hx = __builtin_bit_cast(half2v, x);
    return acc + (float)hw.x * (float)hx.x + (float)hw.y * (float)hx.y;
#endif
}

#define ALOAD(p)      __hip_atomic_load((p), __ATOMIC_RELAXED, __HIP_MEMORY_SCOPE_AGENT)
#define ASTORE(p, v)  __hip_atomic_store((p), (v), __ATOMIC_RELAXED, __HIP_MEMORY_SCOPE_AGENT)

// ---- workspace layout ----
constexpr size_t X0_DW   = (size_t)S_LEN * (DIN0 / 2);            // 4 MB
constexpr size_t X0B     = X0_DW * 4;
constexpr size_t RING_DW = (size_t)NL * RING * HID;               // tagged dwords, 2 MB
constexpr size_t RINGB   = RING_DW * 4;
constexpr size_t WK_DW   = (size_t)NWAVE * SP * 64;               // 65536 dw per block
constexpr size_t WL_DW   = (size_t)NCU_L * WK_DW;
constexpr size_t WB      = (size_t)NL * WL_DW * 4;                // ~67 MB
constexpr size_t FLAG_N  = (size_t)NL * NCU_L + 1;                // prog[4][64] + abort
constexpr size_t TOTAL_WS = X0B + RINGB + WB + FLAG_N * 4;

// ---------------- pre-kernels ----------------

__global__ void conv_x_kernel(const float* __restrict__ x, uint32_t* __restrict__ dst) {
    int i = blockIdx.x * 256 + threadIdx.x;   // exactly X0_DW threads
    float v0 = x[2 * i], v1 = x[2 * i + 1];
    half2v h = {(_Float16)v0, (_Float16)v1};
    dst[i] = __builtin_bit_cast(uint32_t, h);
}

// dst layout: [k(64)][wave(8)][c4(32)][lane(64)][e(4)].
// Column space (halves): [0,1024) = x region (cols >= din zero-padded),
//                        [1024,2048) = h region.
__global__ void pack_weights_kernel(const float* __restrict__ wih, const float* __restrict__ whh,
                                    int din, uint32_t* __restrict__ dst) {
    int i = blockIdx.x * 256 + threadIdx.x;   // exactly WL_DW threads
    int e = i & 3;  int q = i >> 2;
    int l = q & 63; q >>= 6;
    int c4 = q & 31; q >>= 5;
    int w = q & 7;  int k = q >> 3;
    int c = 4 * c4 + e;
    int col = w * 256 + 2 * c;                // half col in [0,2048)
    int row = (l >> 4) * HID + k * 16 + (l & 15);
    float v0, v1;
    {
        int hc = col;
        v0 = (hc < 1024) ? ((hc < din) ? wih[(size_t)row * din + hc] : 0.f)
                         : whh[(size_t)row * HID + (hc - 1024)];
        hc = col + 1;
        v1 = (hc < 1024) ? ((hc < din) ? wih[(size_t)row * din + hc] : 0.f)
                         : whh[(size_t)row * HID + (hc - 1024)];
    }
    half2v h = {(_Float16)v0, (_Float16)v1};
    dst[i] = __builtin_bit_cast(uint32_t, h);
}

__global__ void init_misc_kernel(int* __restrict__ flags, int n, float* __restrict__ out,
                                 const float* __restrict__ fcb) {
    int i = blockIdx.x * 256 + threadIdx.x;
    if (i < n) flags[i] = 0;
    if (i == 0) out[0] = fcb[0];
}

// ---------------- persistent LSTM kernel ----------------

__device__ __forceinline__ float frcp_f(float x) { return __builtin_amdgcn_rcpf(x); }
__device__ __forceinline__ float fsigmoid(float x) { return frcp_f(1.f + __expf(-x)); }
__device__ __forceinline__ float ftanh_c(float x) {
    float e = __expf(-2.f * x);
    return (1.f - e) * frcp_f(1.f + e);
}

// Poll 4 consecutive tagged dwords until all carry `tag` in low 16 bits.
// Single 16B load (sc0 sc1 = bypass caches to the coherence point) per
// iteration; each dword carries its own tag, all 4 must match. Proven R10/R12
// form; pipelined variants (R11/R13) are blacklisted (~9x regressions).
__device__ __forceinline__ v4u poll4(const uint32_t* p, uint32_t tag, int* abortf) {
    v4u d;
    int tries = 0;
    for (;;) {
        asm volatile("global_load_dwordx4 %0, %1, off sc0 sc1\n\ts_waitcnt vmcnt(0)"
                     : "=v"(d) : "v"(p) : "memory");
        uint32_t bad = ((d[0] ^ tag) | (d[1] ^ tag) | (d[2] ^ tag) | (d[3] ^ tag)) & 0xFFFFu;
        if (bad == 0) break;
        if ((++tries & 255) == 0) {
            if (ALOAD(abortf)) break;
            if (tries > (1 << 22)) { ASTORE(abortf, 1); break; }
        }
    }
    return d;
}

#define REP32(M) M(0) M(1) M(2) M(3) M(4) M(5) M(6) M(7) M(8) M(9) M(10) M(11) \
                 M(12) M(13) M(14) M(15) M(16) M(17) M(18) M(19) M(20) M(21) M(22) M(23) \
                 M(24) M(25) M(26) M(27) M(28) M(29) M(30) M(31)

__device__ __forceinline__ void run_layer(
    int k, bool isL0,
    const uint32_t* __restrict__ x0p,     // layer 0 input (packed halves, untagged)
    const uint32_t* up_ring,              // upstream tagged ring (null for L0)
    uint32_t* own_ring,                   // own tagged ring
    const uint32_t* __restrict__ wsrc,
    const float* __restrict__ bias,
    const float* __restrict__ fcw,
    float* out,
    int* prog_own, int* prog_dn, int* abortf, bool doFC)
{
    __shared__ alignas(16) uint32_t in_lds[NWAVE * SP];   // 1024 dw = 4 KB
    __shared__ float red[2][NWAVE][65];                   // parity double buffer

    const int tid  = threadIdx.x;
    const int wave = tid >> 6;
    const int lane = tid & 63;

    // ---- weight slice: 32 v4u via asm loads (non-remat); waves_per_eu(2,2)
    //      gives the 256-VGPR budget they need to stay resident.
    const uint32_t* wb = wsrc + (size_t)wave * (SP * 64) + lane * 4;
#define WLOAD(i) v4u W##i; { const uint32_t* a_ = wb + (size_t)(i) * 256;        \
        asm volatile("global_load_dwordx4 %0, %1, off\n\ts_waitcnt vmcnt(0)"     \
                     : "=v"(W##i) : "v"(a_) : "memory"); }
    REP32(WLOAD)
#undef WLOAD

    // Epilogue mapping (wave 0 only): lane l holds gate-row l of this block:
    // gate = l>>4 (i,f,g,o), h-index j = l&15. Lanes 0-15 finalize h_j.
    const float bval = (wave == 0)
        ? bias[(lane >> 4) * HID + k * 16 + (lane & 15)] : 0.f;
    float fcv = 0.f;
    if (doFC && wave == 0 && lane < 16) fcv = fcw[k * 16 + lane];
    float cst = 0.f, hval = 0.f;

    for (int t = 0; t < S_LEN; ++t) {
        const int slot = t & RMASK;

        // ---- ring-overrun guard (every 32 steps; wave 1) ----
        // Producer will overwrite slots t..t+31 (= x_{t-128}..x_{t-97});
        // require downstream progress >= t-96 before proceeding. barrier2(t)
        // orders this before wave 0's store of slot t.
        if (prog_dn && wave == 1 && t >= RING && (t & 31) == 0) {
            int it = 0;
            for (;;) {
                int ok = (ALOAD(prog_dn + lane) >= t - RING + 32);
                if (__all(ok)) break;
                if ((++it & 255) == 0) {
                    if (ALOAD(abortf)) break;
                    if (it > (1 << 22)) { ASTORE(abortf, 1); break; }
                }
            }
        }

        // ---- wave-private staging: each wave fills ITS OWN in_lds slice ----
        {
            uint32_t dw0, dw1;
            if (tid < 256) {
                if (isL0) {
                    uint64_t v = 0;
                    if (tid < 64) v = *(const uint64_t*)(x0p + (size_t)t * 128 + 2 * tid);
                    dw0 = (uint32_t)v; dw1 = (uint32_t)(v >> 32);
                } else {
                    v4u d = poll4(up_ring + (size_t)slot * HID + 4 * tid, (uint32_t)t, abortf);
                    dw0 = (d[0] >> 16) | (d[1] & 0xFFFF0000u);
                    dw1 = (d[2] >> 16) | (d[3] & 0xFFFF0000u);
                }
            } else {
                if (t) {
                    v4u d = poll4(own_ring + (size_t)((t - 1) & RMASK) * HID + 4 * (tid - 256),
                                  (uint32_t)(t - 1), abortf);
                    dw0 = (d[0] >> 16) | (d[1] & 0xFFFF0000u);
                    dw1 = (d[2] >> 16) | (d[3] & 0xFFFF0000u);
                } else { dw0 = 0u; dw1 = 0u; }
            }
            in_lds[2 * tid] = dw0;
            in_lds[2 * tid + 1] = dw1;
        }
        // NO barrier: in_lds slice is wave-private; same-wave ds_write->ds_read
        // is ordered by the LDS pipe + compiler lgkmcnt.

        // ---- dot: lane = gate row, wave = 256-half column slice ----
        const uint32_t* wi = in_lds + wave * SP;
        float a0 = 0, a1 = 0, a2 = 0, a3 = 0;
#define DOT(i) { v4u x_ = *(const v4u*)&wi[4 * (i)];            \
        a0 = dot2acc(W##i[0], x_[0], a0);                       \
        a1 = dot2acc(W##i[1], x_[1], a1);                       \
        a2 = dot2acc(W##i[2], x_[2], a2);                       \
        a3 = dot2acc(W##i[3], x_[3], a3); }
        DOT(0) DOT(1) DOT(2) DOT(3)
        __builtin_amdgcn_sched_barrier(0);
        DOT(4) DOT(5) DOT(6) DOT(7)
        __builtin_amdgcn_sched_barrier(0);
        DOT(8) DOT(9) DOT(10) DOT(11)
        __builtin_amdgcn_sched_barrier(0);
        DOT(12) DOT(13) DOT(14) DOT(15)
        __builtin_amdgcn_sched_barrier(0);
        DOT(16) DOT(17) DOT(18) DOT(19)
        __builtin_amdgcn_sched_barrier(0);
        DOT(20) DOT(21) DOT(22) DOT(23)
        __builtin_amdgcn_sched_barrier(0);
        DOT(24) DOT(25) DOT(26) DOT(27)
        __builtin_amdgcn_sched_barrier(0);
        DOT(28) DOT(29) DOT(30) DOT(31)
#undef DOT
        red[t & 1][wave][lane] = (a0 + a1) + (a2 + a3);

        __syncthreads();   // the ONLY barrier per step

        // ---- wave-0-only epilogue: gates + coalesced 64B h-publish ----
        // Other waves fall through and start staging step t+1 immediately;
        // their red[(t+1)&1] writes are in the other parity buffer, and their
        // next write to parity (t&1) is after barrier(t+1), which is after
        // this read.
        if (wave == 0) {
            __builtin_amdgcn_s_setprio(1);
            const float* rb = &red[t & 1][0][0];
            float r0 = rb[0 * 65 + lane], r1 = rb[1 * 65 + lane];
            float r2 = rb[2 * 65 + lane], r3 = rb[3 * 65 + lane];
            float r4 = rb[4 * 65 + lane], r5 = rb[5 * 65 + lane];
            float r6 = rb[6 * 65 + lane], r7 = rb[7 * 65 + lane];
            float p = ((r0 + r1) + (r2 + r3)) + ((r4 + r5) + (r6 + r7));
            p += bval;
            p = fminf(15.f, fmaxf(-15.f, p));
            // all-lane transform: lanes 32-47 (gate g) tanh, others sigmoid
            float tv = (((lane >> 4) & 3) == 2) ? ftanh_c(p) : fsigmoid(p);
            float tf = __shfl(tv, (lane & 15) + 16);
            float tg = __shfl(tv, (lane & 15) + 32);
            float to = __shfl(tv, (lane & 15) + 48);
            if (lane < 16) {
                cst = tf * cst + tv * tg;          // f*c + i*g
                float c2 = fminf(15.f, fmaxf(-15.f, cst));
                hval = to * ftanh_c(c2);
                uint32_t hb = (uint32_t)__builtin_bit_cast(unsigned short, (_Float16)hval);
                uint32_t dtag = (hb << 16) | ((uint32_t)t & 0xFFFFu);
                // one wave instruction, 16 contiguous dwords -> one 64B
                // coalesced agent-scope transaction.
                ASTORE(own_ring + (size_t)slot * HID + k * 16 + lane, dtag);
            }
            __builtin_amdgcn_s_setprio(0);
            if (((t & 31) == 31) && lane == 0) ASTORE(prog_own + k, t);
        }
    }

    // ---- final FC (layer 3): y = fc_w . h_last + fc_b ----
    if (doFC && wave == 0) {
        float p = (lane < 16) ? fcv * hval : 0.f;
        p += __shfl_xor(p, 1);
        p += __shfl_xor(p, 2);
        p += __shfl_xor(p, 4);
        p += __shfl_xor(p, 8);
        if (lane == 0) atomicAdd(out, p);
    }
}

__global__ __launch_bounds__(NTHR, 2) __attribute__((amdgpu_waves_per_eu(2, 2)))
void lstm_persistent(
    const uint32_t* __restrict__ x0p,
    uint32_t* ring,
    const uint32_t* __restrict__ wp,
    const float* __restrict__ b0, const float* __restrict__ b1,
    const float* __restrict__ b2, const float* __restrict__ b3,
    const float* __restrict__ fcw, float* out,
    int* flags, int* abortf)
{
    const int bid = blockIdx.x;
    const int xcd = bid & 7;
    const int layer = xcd >> 1;                    // 2 XCDs per layer
    const int k = ((bid >> 3) << 1) | (xcd & 1);   // 0..63 within layer

    const float* bias = (layer == 0) ? b0 : (layer == 1) ? b1 : (layer == 2) ? b2 : b3;
    int* prog_own = flags + layer * NCU_L;
    int* prog_dn  = (layer < 3) ? (flags + (layer + 1) * NCU_L) : nullptr;

    uint32_t* own_ring = ring + (size_t)layer * RING * HID;
    const uint32_t* up_ring = layer ? (ring + (size_t)(layer - 1) * RING * HID) : nullptr;
    const uint32_t* wsrc = wp + (size_t)layer * WL_DW + (size_t)k * WK_DW;

    run_layer(k, layer == 0, x0p, up_ring, own_ring, wsrc, bias, fcw, out,
              prog_own, prog_dn, abortf, layer == 3);
}

// ---------------- host launcher ----------------

extern "C" void kernel_launch(void* const* d_in, const int* in_sizes, int n_in,
                              void* d_out, int out_size, void* d_ws, size_t ws_size,
                              hipStream_t stream) {
    const float* seq  = (const float*)d_in[0];
    const float* wih0 = (const float*)d_in[1];
    const float* whh0 = (const float*)d_in[2];
    const float* b0   = (const float*)d_in[3];
    const float* wih1 = (const float*)d_in[4];
    const float* whh1 = (const float*)d_in[5];
    const float* b1   = (const float*)d_in[6];
    const float* wih2 = (const float*)d_in[7];
    const float* whh2 = (const float*)d_in[8];
    const float* b2   = (const float*)d_in[9];
    const float* wih3 = (const float*)d_in[10];
    const float* whh3 = (const float*)d_in[11];
    const float* b3   = (const float*)d_in[12];
    const float* fcw  = (const float*)d_in[13];
    const float* fcb  = (const float*)d_in[14];
    float* out = (float*)d_out;

    if (ws_size < TOTAL_WS) return;

    uint8_t* ws = (uint8_t*)d_ws;
    uint32_t* x0p  = (uint32_t*)ws;
    uint32_t* ring = (uint32_t*)(ws + X0B);
    uint32_t* wp   = (uint32_t*)(ws + X0B + RINGB);
    int* flags     = (int*)(ws + X0B + RINGB + WB);
    int* abortf    = flags + NL * NCU_L;

    conv_x_kernel<<<(int)(X0_DW / 256), 256, 0, stream>>>(seq, x0p);
    pack_weights_kernel<<<(int)(WL_DW / 256), 256, 0, stream>>>(wih0, whh0, DIN0, wp);
    pack_weights_kernel<<<(int)(WL_DW / 256), 256, 0, stream>>>(wih1, whh1, HID, wp + WL_DW);
    pack_weights_kernel<<<(int)(WL_DW / 256), 256, 0, stream>>>(wih2, whh2, HID, wp + 2 * WL_DW);
    pack_weights_kernel<<<(int)(WL_DW / 256), 256, 0, stream>>>(wih3, whh3, HID, wp + 3 * WL_DW);
    init_misc_kernel<<<(int)((FLAG_N + 255) / 256), 256, 0, stream>>>(flags, (int)FLAG_N, out, fcb);

    lstm_persistent<<<256, NTHR, 0, stream>>>(x0p, ring, wp, b0, b1, b2, b3, fcw, out, flags, abortf);
}

// Round 9
// 15622.685 us; speedup vs baseline: 10.6572x; 1.0016x over previous
//
#include <hip/hip_runtime.h>
#include <stdint.h>

// R16: R15 base (single-barrier, 15.65ms) + safe critical-path trims.
//  - L0 waves 1-3 (zero-padded x columns) skip staging+dots entirely (red
//    zeroed once for both parities) -> less VALU/LDS contention on L0 CUs.
//  - v_perm_b32 repack in staging (2 instrs instead of 6 shifts/masks) on
//    the h-wave post-detect tail.
//  - wave0 keeps its own gate partial in-register: no red[?][0] write, and
//    the epilogue reads only red[1..7] (7 LDS reads instead of 8).
// Blacklists upheld: no pipelined/split-waitcnt polls (R11/R13 9x), no
// s_sleep backoff (R9), fused load+vmcnt(0) single-asm poll only.

#define S_LEN 8192
#define HID   1024
#define DIN0  256
#define NL    4
#define NCU_L 64
#define NTHR  512
#define NWAVE 8
#define SP    128          // weight dwords per lane per wave
#define RING  128
#define RMASK (RING - 1)

typedef _Float16 half2v __attribute__((ext_vector_type(2)));
typedef uint32_t v4u   __attribute__((ext_vector_type(4)));

#if defined(__has_builtin)
#if __has_builtin(__builtin_amdgcn_fdot2)
#define HAVE_FDOT2 1
#endif
#endif

__device__ __forceinline__ float dot2acc(uint32_t w, uint32_t x, float acc) {
#ifdef HAVE_FDOT2
    return __builtin_amdgcn_fdot2(__builtin_bit_cast(half2v, w),
                                  __builtin_bit_cast(half2v, x), acc, false);
#else
    half2v hw = __builtin_bit_cast(half2v, w);
    half2v hx = __builtin_bit_cast(half2v, x);
    return acc + (float)hw.x * (float)hx.x + (float)hw.y * (float)hx.y;
#endif
}

#define ALOAD(p)      __hip_atomic_load((p), __ATOMIC_RELAXED, __HIP_MEMORY_SCOPE_AGENT)
#define ASTORE(p, v)  __hip_atomic_store((p), (v), __ATOMIC_RELAXED, __HIP_MEMORY_SCOPE_AGENT)

// ---- workspace layout ----
constexpr size_t X0_DW   = (size_t)S_LEN * (DIN0 / 2);            // 4 MB
constexpr size_t X0B     = X0_DW * 4;
constexpr size_t RING_DW = (size_t)NL * RING * HID;               // tagged dwords, 2 MB
constexpr size_t RINGB   = RING_DW * 4;
constexpr size_t WK_DW   = (size_t)NWAVE * SP * 64;               // 65536 dw per block
constexpr size_t WL_DW   = (size_t)NCU_L * WK_DW;
constexpr size_t WB      = (size_t)NL * WL_DW * 4;                // ~67 MB
constexpr size_t FLAG_N  = (size_t)NL * NCU_L + 1;                // prog[4][64] + abort
constexpr size_t TOTAL_WS = X0B + RINGB + WB + FLAG_N * 4;

// ---------------- pre-kernels ----------------

__global__ void conv_x_kernel(const float* __restrict__ x, uint32_t* __restrict__ dst) {
    int i = blockIdx.x * 256 + threadIdx.x;   // exactly X0_DW threads
    float v0 = x[2 * i], v1 = x[2 * i + 1];
    half2v h = {(_Float16)v0, (_Float16)v1};
    dst[i] = __builtin_bit_cast(uint32_t, h);
}

// dst layout: [k(64)][wave(8)][c4(32)][lane(64)][e(4)].
// Column space (halves): [0,1024) = x region (cols >= din zero-padded),
//                        [1024,2048) = h region.
__global__ void pack_weights_kernel(const float* __restrict__ wih, const float* __restrict__ whh,
                                    int din, uint32_t* __restrict__ dst) {
    int i = blockIdx.x * 256 + threadIdx.x;   // exactly WL_DW threads
    int e = i & 3;  int q = i >> 2;
    int l = q & 63; q >>= 6;
    int c4 = q & 31; q >>= 5;
    int w = q & 7;  int k = q >> 3;
    int c = 4 * c4 + e;
    int col = w * 256 + 2 * c;                // half col in [0,2048)
    int row = (l >> 4) * HID + k * 16 + (l & 15);
    float v0, v1;
    {
        int hc = col;
        v0 = (hc < 1024) ? ((hc < din) ? wih[(size_t)row * din + hc] : 0.f)
                         : whh[(size_t)row * HID + (hc - 1024)];
        hc = col + 1;
        v1 = (hc < 1024) ? ((hc < din) ? wih[(size_t)row * din + hc] : 0.f)
                         : whh[(size_t)row * HID + (hc - 1024)];
    }
    half2v h = {(_Float16)v0, (_Float16)v1};
    dst[i] = __builtin_bit_cast(uint32_t, h);
}

__global__ void init_misc_kernel(int* __restrict__ flags, int n, float* __restrict__ out,
                                 const float* __restrict__ fcb) {
    int i = blockIdx.x * 256 + threadIdx.x;
    if (i < n) flags[i] = 0;
    if (i == 0) out[0] = fcb[0];
}

// ---------------- persistent LSTM kernel ----------------

__device__ __forceinline__ float frcp_f(float x) { return __builtin_amdgcn_rcpf(x); }
__device__ __forceinline__ float fsigmoid(float x) { return frcp_f(1.f + __expf(-x)); }
__device__ __forceinline__ float ftanh_c(float x) {
    float e = __expf(-2.f * x);
    return (1.f - e) * frcp_f(1.f + e);
}

// Poll 4 consecutive tagged dwords until all carry `tag` in low 16 bits.
// Single fused 16B load + vmcnt(0) in ONE asm block (the only proven-safe
// form); sc0 sc1 = bypass caches to the coherence point.
__device__ __forceinline__ v4u poll4(const uint32_t* p, uint32_t tag, int* abortf) {
    v4u d;
    int tries = 0;
    for (;;) {
        asm volatile("global_load_dwordx4 %0, %1, off sc0 sc1\n\ts_waitcnt vmcnt(0)"
                     : "=v"(d) : "v"(p) : "memory");
        uint32_t bad = ((d[0] ^ tag) | (d[1] ^ tag) | (d[2] ^ tag) | (d[3] ^ tag)) & 0xFFFFu;
        if (bad == 0) break;
        if ((++tries & 255) == 0) {
            if (ALOAD(abortf)) break;
            if (tries > (1 << 22)) { ASTORE(abortf, 1); break; }
        }
    }
    return d;
}

// repack: dw = hi16(b) | (hi16(a) kept in place) -- one v_perm_b32.
// result bytes {3,2,1,0} = {a.b3, a.b2, b.b3, b.b2}
__device__ __forceinline__ uint32_t hipack(uint32_t a, uint32_t b) {
    return __builtin_amdgcn_perm(a, b, 0x07060302u);
}

#define REP32(M) M(0) M(1) M(2) M(3) M(4) M(5) M(6) M(7) M(8) M(9) M(10) M(11) \
                 M(12) M(13) M(14) M(15) M(16) M(17) M(18) M(19) M(20) M(21) M(22) M(23) \
                 M(24) M(25) M(26) M(27) M(28) M(29) M(30) M(31)

__device__ __forceinline__ void run_layer(
    int k, bool isL0,
    const uint32_t* __restrict__ x0p,     // layer 0 input (packed halves, untagged)
    const uint32_t* up_ring,              // upstream tagged ring (null for L0)
    uint32_t* own_ring,                   // own tagged ring
    const uint32_t* __restrict__ wsrc,
    const float* __restrict__ bias,
    const float* __restrict__ fcw,
    float* out,
    int* prog_own, int* prog_dn, int* abortf, bool doFC)
{
    __shared__ alignas(16) uint32_t in_lds[NWAVE * SP];   // 1024 dw = 4 KB
    __shared__ float red[2][NWAVE][65];                   // parity double buffer

    const int tid  = threadIdx.x;
    const int wave = tid >> 6;
    const int lane = tid & 63;

    // ---- weight slice: 32 v4u via asm loads (non-remat); waves_per_eu(2,2)
    //      gives the 256-reg budget they need to stay resident.
    const uint32_t* wb = wsrc + (size_t)wave * (SP * 64) + lane * 4;
#define WLOAD(i) v4u W##i; { const uint32_t* a_ = wb + (size_t)(i) * 256;        \
        asm volatile("global_load_dwordx4 %0, %1, off\n\ts_waitcnt vmcnt(0)"     \
                     : "=v"(W##i) : "v"(a_) : "memory"); }
    REP32(WLOAD)
#undef WLOAD

    // L0 waves 1-3 cover zero-padded x columns: skip staging+dots entirely.
    const bool activeWave = !(isL0 && wave >= 1 && wave <= 3);

    // Epilogue mapping (wave 0 only): lane l holds gate-row l of this block:
    // gate = l>>4 (i,f,g,o), h-index j = l&15. Lanes 0-15 finalize h_j.
    const float bval = (wave == 0)
        ? bias[(lane >> 4) * HID + k * 16 + (lane & 15)] : 0.f;
    float fcv = 0.f;
    if (doFC && wave == 0 && lane < 16) fcv = fcw[k * 16 + lane];
    float cst = 0.f, hval = 0.f;

    for (int t = 0; t < S_LEN; ++t) {
        const int slot = t & RMASK;

        // ---- ring-overrun guard (every 32 steps; wave 1) ----
        // Producer will overwrite slots t..t+31 (= x_{t-128}..x_{t-97});
        // require downstream progress >= t-96 before proceeding. barrier(t)
        // orders this before wave 0's store of slot t.
        if (prog_dn && wave == 1 && t >= RING && (t & 31) == 0) {
            int it = 0;
            for (;;) {
                int ok = (ALOAD(prog_dn + lane) >= t - RING + 32);
                if (__all(ok)) break;
                if ((++it & 255) == 0) {
                    if (ALOAD(abortf)) break;
                    if (it > (1 << 22)) { ASTORE(abortf, 1); break; }
                }
            }
        }

        float psum = 0.f;   // this wave's gate partial (row = lane)

        if (activeWave) {
            // ---- wave-private staging: each wave fills ITS OWN slice ----
            uint32_t dw0, dw1;
            if (wave < 4) {
                if (isL0) {
                    // only wave 0 reaches here for L0 (waves 1-3 inactive)
                    uint64_t v = *(const uint64_t*)(x0p + (size_t)t * 128 + 2 * lane);
                    dw0 = (uint32_t)v; dw1 = (uint32_t)(v >> 32);
                } else {
                    v4u d = poll4(up_ring + (size_t)slot * HID + wave * 256 + 4 * lane,
                                  (uint32_t)t, abortf);
                    dw0 = hipack(d[1], d[0]);
                    dw1 = hipack(d[3], d[2]);
                }
            } else {
                if (t) {
                    v4u d = poll4(own_ring + (size_t)((t - 1) & RMASK) * HID
                                  + (wave - 4) * 256 + 4 * lane,
                                  (uint32_t)(t - 1), abortf);
                    dw0 = hipack(d[1], d[0]);
                    dw1 = hipack(d[3], d[2]);
                } else { dw0 = 0u; dw1 = 0u; }
            }
            in_lds[wave * SP + 2 * lane]     = dw0;
            in_lds[wave * SP + 2 * lane + 1] = dw1;
            // NO barrier: slice is wave-private; same-wave ds_write->ds_read
            // is ordered by the LDS pipe + compiler lgkmcnt.

            // ---- dot: lane = gate row, wave = 256-half column slice ----
            const uint32_t* wi = in_lds + wave * SP;
            float a0 = 0, a1 = 0, a2 = 0, a3 = 0;
#define DOT(i) { v4u x_ = *(const v4u*)&wi[4 * (i)];            \
        a0 = dot2acc(W##i[0], x_[0], a0);                       \
        a1 = dot2acc(W##i[1], x_[1], a1);                       \
        a2 = dot2acc(W##i[2], x_[2], a2);                       \
        a3 = dot2acc(W##i[3], x_[3], a3); }
            DOT(0) DOT(1) DOT(2) DOT(3)
            __builtin_amdgcn_sched_barrier(0);
            DOT(4) DOT(5) DOT(6) DOT(7)
            __builtin_amdgcn_sched_barrier(0);
            DOT(8) DOT(9) DOT(10) DOT(11)
            __builtin_amdgcn_sched_barrier(0);
            DOT(12) DOT(13) DOT(14) DOT(15)
            __builtin_amdgcn_sched_barrier(0);
            DOT(16) DOT(17) DOT(18) DOT(19)
            __builtin_amdgcn_sched_barrier(0);
            DOT(20) DOT(21) DOT(22) DOT(23)
            __builtin_amdgcn_sched_barrier(0);
            DOT(24) DOT(25) DOT(26) DOT(27)
            __builtin_amdgcn_sched_barrier(0);
            DOT(28) DOT(29) DOT(30) DOT(31)
#undef DOT
            psum = (a0 + a1) + (a2 + a3);
            // wave 0 keeps its partial in-register (nobody reads red[?][0])
            if (wave != 0) red[t & 1][wave][lane] = psum;
        } else if (t == 0) {
            red[0][wave][lane] = 0.f;
            red[1][wave][lane] = 0.f;
        }

        __syncthreads();   // the ONLY barrier per step

        // ---- wave-0-only epilogue: gates + coalesced 64B h-publish ----
        // Other waves fall through and start staging step t+1 immediately;
        // their red[(t+1)&1] writes are in the other parity buffer, and their
        // next write to parity (t&1) is after barrier(t+1), after this read.
        if (wave == 0) {
            __builtin_amdgcn_s_setprio(1);
            const float* rb = &red[t & 1][0][0];
            float r1 = rb[1 * 65 + lane], r2 = rb[2 * 65 + lane];
            float r3 = rb[3 * 65 + lane], r4 = rb[4 * 65 + lane];
            float r5 = rb[5 * 65 + lane], r6 = rb[6 * 65 + lane];
            float r7 = rb[7 * 65 + lane];
            float p = ((psum + r1) + (r2 + r3)) + ((r4 + r5) + (r6 + r7));
            p += bval;
            p = fminf(15.f, fmaxf(-15.f, p));
            // all-lane transform: lanes 32-47 (gate g) tanh, others sigmoid
            float tv = (((lane >> 4) & 3) == 2) ? ftanh_c(p) : fsigmoid(p);
            float tf = __shfl(tv, (lane & 15) + 16);
            float tg = __shfl(tv, (lane & 15) + 32);
            float to = __shfl(tv, (lane & 15) + 48);
            if (lane < 16) {
                cst = tf * cst + tv * tg;          // f*c + i*g
                float c2 = fminf(15.f, fmaxf(-15.f, cst));
                hval = to * ftanh_c(c2);
                uint32_t hb = (uint32_t)__builtin_bit_cast(unsigned short, (_Float16)hval);
                uint32_t dtag = (hb << 16) | ((uint32_t)t & 0xFFFFu);
                // one wave instruction, 16 contiguous dwords -> one 64B
                // coalesced agent-scope transaction.
                ASTORE(own_ring + (size_t)slot * HID + k * 16 + lane, dtag);
            }
            __builtin_amdgcn_s_setprio(0);
            if (((t & 31) == 31) && lane == 0) ASTORE(prog_own + k, t);
        }
    }

    // ---- final FC (layer 3): y = fc_w . h_last + fc_b ----
    if (doFC && wave == 0) {
        float p = (lane < 16) ? fcv * hval : 0.f;
        p += __shfl_xor(p, 1);
        p += __shfl_xor(p, 2);
        p += __shfl_xor(p, 4);
        p += __shfl_xor(p, 8);
        if (lane == 0) atomicAdd(out, p);
    }
}

__global__ __launch_bounds__(NTHR, 2) __attribute__((amdgpu_waves_per_eu(2, 2)))
void lstm_persistent(
    const uint32_t* __restrict__ x0p,
    uint32_t* ring,
    const uint32_t* __restrict__ wp,
    const float* __restrict__ b0, const float* __restrict__ b1,
    const float* __restrict__ b2, const float* __restrict__ b3,
    const float* __restrict__ fcw, float* out,
    int* flags, int* abortf)
{
    const int bid = blockIdx.x;
    const int xcd = bid & 7;
    const int layer = xcd >> 1;                    // 2 XCDs per layer
    const int k = ((bid >> 3) << 1) | (xcd & 1);   // 0..63 within layer

    const float* bias = (layer == 0) ? b0 : (layer == 1) ? b1 : (layer == 2) ? b2 : b3;
    int* prog_own = flags + layer * NCU_L;
    int* prog_dn  = (layer < 3) ? (flags + (layer + 1) * NCU_L) : nullptr;

    uint32_t* own_ring = ring + (size_t)layer * RING * HID;
    const uint32_t* up_ring = layer ? (ring + (size_t)(layer - 1) * RING * HID) : nullptr;
    const uint32_t* wsrc = wp + (size_t)layer * WL_DW + (size_t)k * WK_DW;

    run_layer(k, layer == 0, x0p, up_ring, own_ring, wsrc, bias, fcw, out,
              prog_own, prog_dn, abortf, layer == 3);
}

// ---------------- host launcher ----------------

extern "C" void kernel_launch(void* const* d_in, const int* in_sizes, int n_in,
                              void* d_out, int out_size, void* d_ws, size_t ws_size,
                              hipStream_t stream) {
    const float* seq  = (const float*)d_in[0];
    const float* wih0 = (const float*)d_in[1];
    const float* whh0 = (const float*)d_in[2];
    const float* b0   = (const float*)d_in[3];
    const float* wih1 = (const float*)d_in[4];
    const float* whh1 = (const float*)d_in[5];
    const float* b1   = (const float*)d_in[6];
    const float* wih2 = (const float*)d_in[7];
    const float* whh2 = (const float*)d_in[8];
    const float* b2   = (const float*)d_in[9];
    const float* wih3 = (const float*)d_in[10];
    const float* whh3 = (const float*)d_in[11];
    const float* b3   = (const float*)d_in[12];
    const float* fcw  = (const float*)d_in[13];
    const float* fcb  = (const float*)d_in[14];
    float* out = (float*)d_out;

    if (ws_size < TOTAL_WS) return;

    uint8_t* ws = (uint8_t*)d_ws;
    uint32_t* x0p  = (uint32_t*)ws;
    uint32_t* ring = (uint32_t*)(ws + X0B);
    uint32_t* wp   = (uint32_t*)(ws + X0B + RINGB);
    int* flags     = (int*)(ws + X0B + RINGB + WB);
    int* abortf    = flags + NL * NCU_L;

    conv_x_kernel<<<(int)(X0_DW / 256), 256, 0, stream>>>(seq, x0p);
    pack_weights_kernel<<<(int)(WL_DW / 256), 256, 0, stream>>>(wih0, whh0, DIN0, wp);
    pack_weights_kernel<<<(int)(WL_DW / 256), 256, 0, stream>>>(wih1, whh1, HID, wp + WL_DW);
    pack_weights_kernel<<<(int)(WL_DW / 256), 256, 0, stream>>>(wih2, whh2, HID, wp + 2 * WL_DW);
    pack_weights_kernel<<<(int)(WL_DW / 256), 256, 0, stream>>>(wih3, whh3, HID, wp + 3 * WL_DW);
    init_misc_kernel<<<(int)((FLAG_N + 255) / 256), 256, 0, stream>>>(flags, (int)FLAG_N, out, fcb);

    lstm_persistent<<<256, NTHR, 0, stream>>>(x0p, ring, wp, b0, b1, b2, b3, fcw, out, flags, abortf);
}